// Round 1
// baseline (241.182 us; speedup 1.0000x reference)
//
#include <hip/hip_runtime.h>
#include <math.h>

#define Bn 128
#define Sn 200
#define Vn 64
#define NC3n 4000

// ws layout (floats)
#define WS_U   0
#define WS_W0  192
#define WS_W1  384
#define WS_A2  576
#define WS_B2  640
#define WS_C20 704
#define WS_C21 768
// total 832 floats

__global__ __launch_bounds__(256) void precompute_kernel(
    const float* __restrict__ v_c3, const float* __restrict__ v_d,
    const float* __restrict__ R_w, const float* __restrict__ W_ih,
    const float* __restrict__ b_ih, const float* __restrict__ l2_w1,
    const float* __restrict__ l2_b1, float* __restrict__ ws)
{
    int j = threadIdx.x;
    if (j < 192) {
        float u = 0.f, w0 = 0.f, w1 = 0.f;
        const float* row = W_ih + j * 128;
        for (int k = 0; k < 64; ++k) {
            u  += row[k]      * v_d[k];
            w0 += row[64 + k] * R_w[k];
            w1 += row[64 + k] * R_w[64 + k];
        }
        ws[WS_U + j]  = u;
        ws[WS_W0 + j] = w0 + b_ih[j];
        ws[WS_W1 + j] = w1 + b_ih[j];
    }
    if (j < 64) {
        float a2 = 0.f, b2 = 0.f, c0 = 0.f, c1 = 0.f;
        const float* row = l2_w1 + j * 192;
        for (int k = 0; k < 64; ++k) {
            a2 += row[k]       * v_c3[k];
            b2 += row[64 + k]  * v_d[k];
            c0 += row[128 + k] * R_w[k];
            c1 += row[128 + k] * R_w[64 + k];
        }
        ws[WS_A2 + j]  = a2;
        ws[WS_B2 + j]  = b2;
        ws[WS_C20 + j] = c0 + l2_b1[j];
        ws[WS_C21 + j] = c1 + l2_b1[j];
    }
}

__device__ __forceinline__ float sigmf(float x) { return 1.f / (1.f + __expf(-x)); }

__global__ __launch_bounds__(256) void scan_kernel(
    const int* __restrict__ c3_seq, const int* __restrict__ d_seq,
    const int* __restrict__ r_seq, const float* __restrict__ D_w,
    const float* __restrict__ W_hh, const float* __restrict__ b_hh,
    const float* __restrict__ l1_w1, const float* __restrict__ l1_b1,
    const float* __restrict__ l1_w2, const float* __restrict__ l1_b2,
    const float* __restrict__ l2_w2, const float* __restrict__ l2_b2,
    const float* __restrict__ ws,
    float* __restrict__ out_alpha, float* __restrict__ out_h,
    float* __restrict__ out_c3)
{
    __shared__ __align__(16) float h_lds[64];
    __shared__ float hg_lds[192];
    __shared__ float gam_lds[Sn];
    __shared__ int   r_lds[Sn];
    __shared__ int   c3_lds[Sn];
    __shared__ float vals_lds[Sn];
    __shared__ float c3state[NC3n];

    const int tid = threadIdx.x;
    const int bid = blockIdx.x;

    if (bid < Bn) {
        // ---------------- GRU + mlp1 + alpha chain, one batch row ----------------
        const int b = bid;
        if (tid < Sn) {
            gam_lds[tid] = D_w[d_seq[b * Sn + tid]];
            r_lds[tid]   = r_seq[b * Sn + tid];
        }
        float w[64];     // W_hh row (tid < 192)
        float l1row[64]; // l1_w1 row (tid < 64)
        float uj=0,u1=0,u2=0,w00=0,w01=0,w02=0,w10=0,w11=0,w12=0,bhh=0;
        float l1b=0, l1w2v=0;
        if (tid < 192) {
            const float4* wr = (const float4*)(W_hh + tid * 64);
            #pragma unroll
            for (int k = 0; k < 16; ++k) {
                float4 v = wr[k];
                w[4*k+0]=v.x; w[4*k+1]=v.y; w[4*k+2]=v.z; w[4*k+3]=v.w;
            }
            bhh = b_hh[tid];
        }
        if (tid < 64) {
            uj  = ws[WS_U+tid];     u1  = ws[WS_U+64+tid];  u2  = ws[WS_U+128+tid];
            w00 = ws[WS_W0+tid];    w01 = ws[WS_W0+64+tid]; w02 = ws[WS_W0+128+tid];
            w10 = ws[WS_W1+tid];    w11 = ws[WS_W1+64+tid]; w12 = ws[WS_W1+128+tid];
            const float4* lr = (const float4*)(l1_w1 + tid * 64);
            #pragma unroll
            for (int k = 0; k < 16; ++k) {
                float4 v = lr[k];
                l1row[4*k+0]=v.x; l1row[4*k+1]=v.y; l1row[4*k+2]=v.z; l1row[4*k+3]=v.w;
            }
            l1b = l1_b1[tid]; l1w2v = l1_w2[tid];
            h_lds[tid] = 0.f;
        }
        float h = 0.f;
        float alpha = 0.f;
        const float l1b2 = l1_b2[0];
        __syncthreads();

        for (int t = 0; t < Sn; ++t) {
            if (tid < 192) {
                float acc = bhh;
                const float4* h4 = (const float4*)h_lds;
                #pragma unroll
                for (int k = 0; k < 16; ++k) {
                    float4 hv = h4[k];
                    acc += w[4*k+0]*hv.x + w[4*k+1]*hv.y + w[4*k+2]*hv.z + w[4*k+3]*hv.w;
                }
                hg_lds[tid] = acc;
            }
            __syncthreads();
            if (tid < 64) {
                float gam = gam_lds[t];
                int   r   = r_lds[t];
                float xr = gam*uj + (r ? w10 : w00);
                float xz = gam*u1 + (r ? w11 : w01);
                float xn = gam*u2 + (r ? w12 : w02);
                float hr = hg_lds[tid], hz = hg_lds[64+tid], hn = hg_lds[128+tid];
                float rg = sigmf(xr + hr);
                float zg = sigmf(xz + hz);
                float e2 = __expf(2.f * (xn + rg*hn));
                float ng = (e2 - 1.f) / (e2 + 1.f);    // tanh
                h = (1.f - zg)*ng + zg*h;
                h_lds[tid] = h;
                out_h[(size_t)(b*Sn + t)*64 + tid] = h;
                // mlp1 (reads h_lds written by this same wave — in-order LDS)
                float acc1 = l1b;
                const float4* h4 = (const float4*)h_lds;
                #pragma unroll
                for (int k = 0; k < 16; ++k) {
                    float4 hv = h4[k];
                    acc1 += l1row[4*k+0]*hv.x + l1row[4*k+1]*hv.y + l1row[4*k+2]*hv.z + l1row[4*k+3]*hv.w;
                }
                float v = fmaxf(acc1, 0.f) * l1w2v;
                #pragma unroll
                for (int off = 32; off > 0; off >>= 1)
                    v += __shfl_down(v, off);
                if (tid == 0) {
                    float an = v + l1b2;
                    bool cond = (alpha - gam) >= 0.f;
                    alpha = (r == 1) ? (cond ? an : alpha) : (cond ? alpha : an);
                    out_alpha[b*Sn + t] = alpha;
                }
            }
            __syncthreads();
        }
    } else {
        // ---------------- C3/mlp2 chain + C3_seq forward-fill, one batch row ----------------
        const int b = bid - Bn;
        if (tid < Sn) {
            gam_lds[tid] = D_w[d_seq[b*Sn + tid]];
            r_lds[tid]   = r_seq[b*Sn + tid];
            c3_lds[tid]  = c3_seq[b*Sn + tid];
        }
        for (int i = tid; i < NC3n; i += 256) c3state[i] = 0.f;
        __syncthreads();
        if (tid < 64) {
            float a2 = ws[WS_A2+tid], b2 = ws[WS_B2+tid];
            float c0 = ws[WS_C20+tid], c1 = ws[WS_C21+tid];
            float w2 = l2_w2[tid];
            float l2b2 = l2_b2[0];
            for (int t = 0; t < Sn; ++t) {
                int   c3   = c3_lds[t];
                float beta = c3state[c3];
                float gam  = gam_lds[t];
                int   r    = r_lds[t];
                float tt = fmaxf(beta*a2 + gam*b2 + (r ? c1 : c0), 0.f);
                float v = tt * w2;
                #pragma unroll
                for (int off = 32; off > 0; off >>= 1)
                    v += __shfl_down(v, off);
                if (tid == 0) {
                    float val = v + l2b2;
                    c3state[c3]  = val;
                    vals_lds[t]  = val;
                }
            }
        }
        __syncthreads();
        // forward-fill the full [Sn][NC3] slab for this row (coalesced float4 streams)
        for (int p = 0; p < 4; ++p) {
            int base = p*1024 + tid*4;
            if (base < NC3n) {
                float4 cur = make_float4(0.f, 0.f, 0.f, 0.f);
                float* outp = out_c3 + (size_t)b*Sn*NC3n + base;
                for (int t = 0; t < Sn; ++t) {
                    int   c3  = c3_lds[t];
                    float val = vals_lds[t];
                    cur.x = (c3 == base    ) ? val : cur.x;
                    cur.y = (c3 == base + 1) ? val : cur.y;
                    cur.z = (c3 == base + 2) ? val : cur.z;
                    cur.w = (c3 == base + 3) ? val : cur.w;
                    *(float4*)outp = cur;
                    outp += NC3n;
                }
            }
        }
    }
}

extern "C" void kernel_launch(void* const* d_in, const int* in_sizes, int n_in,
                              void* d_out, int out_size, void* d_ws, size_t ws_size,
                              hipStream_t stream)
{
    const int*   c3_seq = (const int*)  d_in[0];
    const int*   d_seq  = (const int*)  d_in[1];
    const int*   r_seq  = (const int*)  d_in[2];
    const float* v_c3   = (const float*)d_in[3];
    const float* D_w    = (const float*)d_in[4];
    const float* v_d    = (const float*)d_in[5];
    const float* R_w    = (const float*)d_in[6];
    const float* W_ih   = (const float*)d_in[7];
    const float* W_hh   = (const float*)d_in[8];
    const float* b_ih   = (const float*)d_in[9];
    const float* b_hh   = (const float*)d_in[10];
    const float* l1_w1  = (const float*)d_in[11];
    const float* l1_b1  = (const float*)d_in[12];
    const float* l1_w2  = (const float*)d_in[13];
    const float* l1_b2  = (const float*)d_in[14];
    const float* l2_w1  = (const float*)d_in[15];
    const float* l2_b1  = (const float*)d_in[16];
    const float* l2_w2  = (const float*)d_in[17];
    const float* l2_b2  = (const float*)d_in[18];

    float* ws        = (float*)d_ws;
    float* out_alpha = (float*)d_out;
    float* out_h     = out_alpha + Bn*Sn;
    float* out_c3    = out_h + (size_t)Bn*Sn*Vn;

    precompute_kernel<<<1, 256, 0, stream>>>(v_c3, v_d, R_w, W_ih, b_ih, l2_w1, l2_b1, ws);
    scan_kernel<<<256, 256, 0, stream>>>(c3_seq, d_seq, r_seq, D_w, W_hh, b_hh,
                                         l1_w1, l1_b1, l1_w2, l1_b2, l2_w2, l2_b2,
                                         ws, out_alpha, out_h, out_c3);
}

// Round 2
// 202.554 us; speedup vs baseline: 1.1907x; 1.1907x over previous
//
#include <hip/hip_runtime.h>
#include <math.h>

#define Bn 128
#define Sn 200
#define Vn 64
#define NC3n 4000
#define GRU_BLOCKS 128
#define CHUNKS 4               // 4 chunks x 1000 floats = 4000 columns
#define FILL_BLOCKS (Bn * CHUNKS)

// ws layout (floats)
#define WS_U   0
#define WS_W0  192
#define WS_W1  384
#define WS_A2  576
#define WS_B2  640
#define WS_C20 704
#define WS_C21 768
// total 832 floats

__global__ __launch_bounds__(256) void precompute_kernel(
    const float* __restrict__ v_c3, const float* __restrict__ v_d,
    const float* __restrict__ R_w, const float* __restrict__ W_ih,
    const float* __restrict__ b_ih, const float* __restrict__ l2_w1,
    const float* __restrict__ l2_b1, float* __restrict__ ws)
{
    int j = threadIdx.x;
    if (j < 192) {
        float u = 0.f, w0 = 0.f, w1 = 0.f;
        const float* row = W_ih + j * 128;
        for (int k = 0; k < 64; ++k) {
            u  += row[k]      * v_d[k];
            w0 += row[64 + k] * R_w[k];
            w1 += row[64 + k] * R_w[64 + k];
        }
        ws[WS_U + j]  = u;
        ws[WS_W0 + j] = w0 + b_ih[j];
        ws[WS_W1 + j] = w1 + b_ih[j];
    }
    if (j < 64) {
        float a2 = 0.f, b2 = 0.f, c0 = 0.f, c1 = 0.f;
        const float* row = l2_w1 + j * 192;
        for (int k = 0; k < 64; ++k) {
            a2 += row[k]       * v_c3[k];
            b2 += row[64 + k]  * v_d[k];
            c0 += row[128 + k] * R_w[k];
            c1 += row[128 + k] * R_w[64 + k];
        }
        ws[WS_A2 + j]  = a2;
        ws[WS_B2 + j]  = b2;
        ws[WS_C20 + j] = c0 + l2_b1[j];
        ws[WS_C21 + j] = c1 + l2_b1[j];
    }
}

__device__ __forceinline__ float sigmf(float x) { return 1.f / (1.f + __expf(-x)); }

__global__ __launch_bounds__(256) void scan_kernel(
    const int* __restrict__ c3_seq, const int* __restrict__ d_seq,
    const int* __restrict__ r_seq, const float* __restrict__ D_w,
    const float* __restrict__ W_hh, const float* __restrict__ b_hh,
    const float* __restrict__ l1_w1, const float* __restrict__ l1_b1,
    const float* __restrict__ l1_w2, const float* __restrict__ l1_b2,
    const float* __restrict__ l2_w2, const float* __restrict__ l2_b2,
    const float* __restrict__ ws,
    float* __restrict__ out_alpha, float* __restrict__ out_h,
    float* __restrict__ out_c3)
{
    __shared__ __align__(16) float h_lds[64];
    __shared__ float hg_lds[192];
    __shared__ float gam_lds[Sn];
    __shared__ int   r_lds[Sn];
    __shared__ int   c3_lds[Sn];
    __shared__ float val_lds[Sn];
    __shared__ int   succ_lds[Sn];
    __shared__ int   root_lds[Sn];
    __shared__ float wsA[64], wsB[64], wsC0[64], wsC1[64], wsW2[64];
    __shared__ float l2b2_sh;

    const int tid = threadIdx.x;
    const int bid = blockIdx.x;

    if (bid < GRU_BLOCKS) {
        // ============ GRU + mlp1 + alpha chain, one batch row ============
        const int b = bid;
        if (tid < Sn) {
            gam_lds[tid] = D_w[d_seq[b * Sn + tid]];
            r_lds[tid]   = r_seq[b * Sn + tid];
        }
        float w[64];       // W_hh row (threads 64..255 -> rows 0..191)
        float l1row[64];   // l1_w1 row (threads 0..63)
        float uj=0,u1=0,u2=0,w00=0,w01=0,w02=0,w10=0,w11=0,w12=0,bhh=0;
        float l1b=0, l1w2v=0, l1b2c=0;
        if (tid >= 64) {
            const int rho = tid - 64;
            const float4* wr = (const float4*)(W_hh + rho * 64);
            #pragma unroll
            for (int k = 0; k < 16; ++k) {
                float4 v = wr[k];
                w[4*k+0]=v.x; w[4*k+1]=v.y; w[4*k+2]=v.z; w[4*k+3]=v.w;
            }
            bhh = b_hh[rho];
            hg_lds[rho] = bhh;          // h0 = 0 -> hg(t=0) = b_hh
        } else {
            uj  = ws[WS_U+tid];     u1  = ws[WS_U+64+tid];  u2  = ws[WS_U+128+tid];
            w00 = ws[WS_W0+tid];    w01 = ws[WS_W0+64+tid]; w02 = ws[WS_W0+128+tid];
            w10 = ws[WS_W1+tid];    w11 = ws[WS_W1+64+tid]; w12 = ws[WS_W1+128+tid];
            const float4* lr = (const float4*)(l1_w1 + tid * 64);
            #pragma unroll
            for (int k = 0; k < 16; ++k) {
                float4 v = lr[k];
                l1row[4*k+0]=v.x; l1row[4*k+1]=v.y; l1row[4*k+2]=v.z; l1row[4*k+3]=v.w;
            }
            l1b = l1_b1[tid]; l1w2v = l1_w2[tid]; l1b2c = l1_b2[0];
        }
        float h = 0.f, alpha = 0.f;
        __syncthreads();

        for (int t = 0; t < Sn; ++t) {
            // S1: wave0 computes gates -> h_t
            if (tid < 64) {
                float gam = gam_lds[t];
                int   r   = r_lds[t];
                float xr = gam*uj + (r ? w10 : w00);
                float xz = gam*u1 + (r ? w11 : w01);
                float xn = gam*u2 + (r ? w12 : w02);
                float hr = hg_lds[tid], hz = hg_lds[64+tid], hn = hg_lds[128+tid];
                float rg = sigmf(xr + hr);
                float zg = sigmf(xz + hz);
                float e2 = __expf(2.f * (xn + rg*hn));
                float ng = (e2 - 1.f) / (e2 + 1.f);    // tanh
                h = (1.f - zg)*ng + zg*h;
                h_lds[tid] = h;
                out_h[(size_t)(b*Sn + t)*64 + tid] = h;
            }
            __syncthreads();
            // S2: waves1-3 matvec for t+1 ; wave0 does mlp1 + alpha (overlapped)
            if (tid >= 64) {
                const int rho = tid - 64;
                float a0=0.f,a1=0.f,a2=0.f,a3=0.f;
                const float4* h4 = (const float4*)h_lds;
                #pragma unroll
                for (int k = 0; k < 16; ++k) {
                    float4 hv = h4[k];
                    a0 += w[4*k+0]*hv.x; a1 += w[4*k+1]*hv.y;
                    a2 += w[4*k+2]*hv.z; a3 += w[4*k+3]*hv.w;
                }
                hg_lds[rho] = bhh + ((a0+a1)+(a2+a3));
            } else {
                float a0=0.f,a1=0.f,a2=0.f,a3=0.f;
                const float4* h4 = (const float4*)h_lds;
                #pragma unroll
                for (int k = 0; k < 16; ++k) {
                    float4 hv = h4[k];
                    a0 += l1row[4*k+0]*hv.x; a1 += l1row[4*k+1]*hv.y;
                    a2 += l1row[4*k+2]*hv.z; a3 += l1row[4*k+3]*hv.w;
                }
                float v = fmaxf(l1b + ((a0+a1)+(a2+a3)), 0.f) * l1w2v;
                #pragma unroll
                for (int off = 32; off > 0; off >>= 1)
                    v += __shfl_xor(v, off);
                if (tid == 0) {
                    float gam = gam_lds[t];
                    int   r   = r_lds[t];
                    float an = v + l1b2c;
                    bool cond = (alpha - gam) >= 0.f;
                    alpha = (r == 1) ? (cond ? an : alpha) : (cond ? alpha : an);
                    out_alpha[b*Sn + t] = alpha;
                }
            }
            __syncthreads();
        }
    } else {
        // ============ C3 chain (parallel over chains) + fill, one (row, chunk) ============
        const int fb    = bid - GRU_BLOCKS;
        const int b     = fb >> 2;
        const int chunk = fb & 3;
        if (tid < Sn) {
            gam_lds[tid] = D_w[d_seq[b*Sn + tid]];
            r_lds[tid]   = r_seq[b*Sn + tid];
            c3_lds[tid]  = c3_seq[b*Sn + tid];
        }
        if (tid < 64) {
            wsA[tid]  = ws[WS_A2+tid];  wsB[tid]  = ws[WS_B2+tid];
            wsC0[tid] = ws[WS_C20+tid]; wsC1[tid] = ws[WS_C21+tid];
            wsW2[tid] = l2_w2[tid];
        }
        if (tid == 0) l2b2_sh = l2_b2[0];
        __syncthreads();
        // predecessor / successor links per timestep (same c3 index)
        if (tid < Sn) {
            int c = c3_lds[tid];
            int s = -1;
            for (int u = tid + 1; u < Sn; ++u)
                if (c3_lds[u] == c) { s = u; break; }
            succ_lds[tid] = s;
            int rt = 1;
            for (int u = 0; u < tid; ++u)
                if (c3_lds[u] == c) { rt = 0; break; }
            root_lds[tid] = rt;
        }
        __syncthreads();
        // walk each dependency chain with a 16-lane group (16 groups/block)
        {
            const int g  = tid >> 4;
            const int l  = tid & 15;
            const int j0 = l * 4;
            float A0=wsA[j0],  A1=wsA[j0+1],  A2=wsA[j0+2],  A3=wsA[j0+3];
            float B0=wsB[j0],  B1=wsB[j0+1],  B2=wsB[j0+2],  B3=wsB[j0+3];
            float C00=wsC0[j0],C01=wsC0[j0+1],C02=wsC0[j0+2],C03=wsC0[j0+3];
            float C10=wsC1[j0],C11=wsC1[j0+1],C12=wsC1[j0+2],C13=wsC1[j0+3];
            float W0=wsW2[j0], W1=wsW2[j0+1], W2v=wsW2[j0+2],W3=wsW2[j0+3];
            float l2b2 = l2b2_sh;
            for (int t0 = g; t0 < Sn; t0 += 16) {
                if (!root_lds[t0]) continue;
                float beta = 0.f;
                int t = t0;
                while (t >= 0) {
                    float gam = gam_lds[t];
                    int   r   = r_lds[t];
                    float s = W0*fmaxf(A0*beta + B0*gam + (r ? C10 : C00), 0.f)
                            + W1*fmaxf(A1*beta + B1*gam + (r ? C11 : C01), 0.f)
                            + W2v*fmaxf(A2*beta + B2*gam + (r ? C12 : C02), 0.f)
                            + W3*fmaxf(A3*beta + B3*gam + (r ? C13 : C03), 0.f);
                    s += __shfl_xor(s, 1, 16);
                    s += __shfl_xor(s, 2, 16);
                    s += __shfl_xor(s, 4, 16);
                    s += __shfl_xor(s, 8, 16);
                    beta = s + l2b2;            // uniform across the 16 lanes
                    if (l == 0) val_lds[t] = beta;
                    t = succ_lds[t];
                }
            }
        }
        __syncthreads();
        // stream the forward-filled chunk: 1000 floats x 200 steps (coalesced f4)
        if (tid < 250) {
            const int col = chunk * 1000 + tid * 4;
            float4 cur = make_float4(0.f, 0.f, 0.f, 0.f);
            float* outp = out_c3 + (size_t)b * Sn * NC3n + col;
            #pragma unroll 4
            for (int t = 0; t < Sn; ++t) {
                int   d = c3_lds[t] - col;
                float v = val_lds[t];
                cur.x = (d == 0) ? v : cur.x;
                cur.y = (d == 1) ? v : cur.y;
                cur.z = (d == 2) ? v : cur.z;
                cur.w = (d == 3) ? v : cur.w;
                *(float4*)outp = cur;
                outp += NC3n;
            }
        }
    }
}

extern "C" void kernel_launch(void* const* d_in, const int* in_sizes, int n_in,
                              void* d_out, int out_size, void* d_ws, size_t ws_size,
                              hipStream_t stream)
{
    const int*   c3_seq = (const int*)  d_in[0];
    const int*   d_seq  = (const int*)  d_in[1];
    const int*   r_seq  = (const int*)  d_in[2];
    const float* v_c3   = (const float*)d_in[3];
    const float* D_w    = (const float*)d_in[4];
    const float* v_d    = (const float*)d_in[5];
    const float* R_w    = (const float*)d_in[6];
    const float* W_ih   = (const float*)d_in[7];
    const float* W_hh   = (const float*)d_in[8];
    const float* b_ih   = (const float*)d_in[9];
    const float* b_hh   = (const float*)d_in[10];
    const float* l1_w1  = (const float*)d_in[11];
    const float* l1_b1  = (const float*)d_in[12];
    const float* l1_w2  = (const float*)d_in[13];
    const float* l1_b2  = (const float*)d_in[14];
    const float* l2_w1  = (const float*)d_in[15];
    const float* l2_b1  = (const float*)d_in[16];
    const float* l2_w2  = (const float*)d_in[17];
    const float* l2_b2  = (const float*)d_in[18];

    float* ws        = (float*)d_ws;
    float* out_alpha = (float*)d_out;
    float* out_h     = out_alpha + Bn*Sn;
    float* out_c3    = out_h + (size_t)Bn*Sn*Vn;

    precompute_kernel<<<1, 256, 0, stream>>>(v_c3, v_d, R_w, W_ih, b_ih, l2_w1, l2_b1, ws);
    scan_kernel<<<GRU_BLOCKS + FILL_BLOCKS, 256, 0, stream>>>(
        c3_seq, d_seq, r_seq, D_w, W_hh, b_hh,
        l1_w1, l1_b1, l1_w2, l1_b2, l2_w2, l2_b2,
        ws, out_alpha, out_h, out_c3);
}